// Round 8
// baseline (771.050 us; speedup 1.0000x reference)
//
#include <hip/hip_runtime.h>
#include <math.h>

#define HIDC 128
#define INC 100
#define OUTC 47

typedef __attribute__((ext_vector_type(8))) short short8_t;   // 8 bf16 (4 VGPRs)
typedef __attribute__((ext_vector_type(4))) float f32x4;      // MFMA accumulator

__device__ inline unsigned short f2bf(float f) {
    unsigned u = __builtin_bit_cast(unsigned, f);
    unsigned r = (u + 0x7FFFu + ((u >> 16) & 1u)) >> 16;      // RNE
    return (unsigned short)r;
}
__device__ inline float bf2f(unsigned short s) {
    unsigned u = ((unsigned)s) << 16;
    return __builtin_bit_cast(float, u);
}

// ---------------- CSR build ----------------

__global__ __launch_bounds__(256) void k_deg(const int* __restrict__ dst, int* __restrict__ deg, int ne) {
    int e = blockIdx.x * 256 + threadIdx.x;
    if (e < ne) atomicAdd(&deg[dst[e]], 1);
}

__global__ __launch_bounds__(256) void k_scan1(const int* __restrict__ deg, int* __restrict__ local_s,
                                               int* __restrict__ bsum, int n) {
    __shared__ int s[256];
    int t = threadIdx.x;
    int i = blockIdx.x * 256 + t;
    int v = (i < n) ? deg[i] : 0;
    s[t] = v;
    __syncthreads();
    for (int off = 1; off < 256; off <<= 1) {
        int add = (t >= off) ? s[t - off] : 0;
        __syncthreads();
        s[t] += add;
        __syncthreads();
    }
    if (i < n) local_s[i] = s[t] - v;
    if (t == 255) bsum[blockIdx.x] = s[255];
}

__global__ __launch_bounds__(512) void k_scan2(int* __restrict__ bsum, int nb) {
    __shared__ int s[512];
    int t = threadIdx.x;
    int v = (t < nb) ? bsum[t] : 0;
    s[t] = v;
    __syncthreads();
    for (int off = 1; off < 512; off <<= 1) {
        int add = (t >= off) ? s[t - off] : 0;
        __syncthreads();
        s[t] += add;
        __syncthreads();
    }
    if (t < nb) bsum[t] = s[t] - v;
}

__global__ __launch_bounds__(256) void k_scan3(const int* __restrict__ local_s, const int* __restrict__ bsum,
                                               int* __restrict__ offs, int n, int ne) {
    int i = blockIdx.x * 256 + threadIdx.x;
    if (i < n) offs[i] = local_s[i] + bsum[blockIdx.x];
    if (i == 0) offs[n] = ne;
}

__global__ __launch_bounds__(256) void k_invdeg(const int* __restrict__ deg, float* __restrict__ invdeg, int n) {
    int i = blockIdx.x * 256 + threadIdx.x;
    if (i < n) invdeg[i] = 1.0f / (float)max(deg[i], 1);
}

// Partitioned fill: p = blockIdx.x & 7 over edge chunk blockIdx.x >> 3.

__global__ __launch_bounds__(256) void k_fill(const int* __restrict__ src, const int* __restrict__ dst,
                                              const int* __restrict__ offs, int* __restrict__ curs,
                                              int* __restrict__ csr, int ne, int psize, int ch) {
    int p = blockIdx.x & 7;
    int chunk = blockIdx.x >> 3;
    int lo = p * psize;
    int e0 = chunk * ch;
    int e1 = min(ne, e0 + ch);
    for (int e = e0 + threadIdx.x; e < e1; e += 256) {
        int d = dst[e];
        if ((unsigned)(d - lo) < (unsigned)psize) {
            int pos = atomicAdd(&curs[d], 1);
            csr[offs[d] + pos] = src[e];
        }
    }
}

// ---------------- Weight prep ----------------

__global__ __launch_bounds__(256) void k_prepw(const float* __restrict__ wl_h, const float* __restrict__ wr_h,
                                               unsigned short* __restrict__ wt) {
    int idx = blockIdx.x * 256 + threadIdx.x;
    if (idx >= 6 * 16384) return;
    int m = idx >> 14, rem = idx & 16383;
    int l = m >> 1, s = m & 1;
    const float* srcm = (s == 0 ? wl_h : wr_h) + (size_t)l * 16384;
    wt[idx] = f2bf(srcm[(rem & 127) * 128 + (rem >> 7)]);
}

__global__ __launch_bounds__(256) void k_prepw_out(const float* __restrict__ wl_out,
                                                   const float* __restrict__ wr_out,
                                                   unsigned short* __restrict__ wt2) {
    int idx = blockIdx.x * 256 + threadIdx.x;
    if (idx >= 2 * 48 * 128) return;
    int s = idx / (48 * 128), rem = idx % (48 * 128);
    int nc = rem >> 7, k = rem & 127;
    const float* srcm = (s == 0) ? wl_out : wr_out;
    wt2[idx] = (nc < OUTC) ? f2bf(srcm[k * OUTC + nc]) : 0;
}

__global__ __launch_bounds__(256) void k_prepw_in(const float* __restrict__ w,
                                                  unsigned short* __restrict__ wtin) {
    int idx = blockIdx.x * 256 + threadIdx.x;
    if (idx >= 128 * 128) return;
    int nc = idx >> 7, k = idx & 127;
    wtin[idx] = (k < INC) ? f2bf(w[k * HIDC + nc]) : 0;
}

// ---------------- Input projection via MFMA ----------------

__global__ __launch_bounds__(256) void k_inproj_mfma(const float* __restrict__ x,
                                                     const unsigned short* __restrict__ wtin, // [128][128]
                                                     const float* __restrict__ b,
                                                     unsigned short* __restrict__ inp,
                                                     unsigned short* __restrict__ h, int n) {
    __shared__ unsigned short sX[32 * 128];
    int t = threadIdx.x;
    int w = t >> 6, lane = t & 63;
    int cc = lane & 15, kg = lane >> 4;
    int row0 = blockIdx.x * 32;

    short8_t bfrag[2][4];
#pragma unroll
    for (int ci = 0; ci < 2; ci++) {
        int ncol = 32 * w + ci * 16 + cc;
        const unsigned short* bp = wtin + ncol * 128 + kg * 8;
#pragma unroll
        for (int ks = 0; ks < 4; ks++)
            bfrag[ci][ks] = *reinterpret_cast<const short8_t*>(bp + ks * 32);
    }

    {
        int r = t >> 3, seg = t & 7;
        int row = row0 + r;
        float v[16];
#pragma unroll
        for (int i = 0; i < 16; i++) v[i] = 0.f;
        if (row < n) {
            const float* xr = x + (size_t)row * INC;
            if (seg < 6) {
#pragma unroll
                for (int j = 0; j < 4; j++) {
                    float4 f = *reinterpret_cast<const float4*>(xr + seg * 16 + j * 4);
                    v[j * 4 + 0] = f.x; v[j * 4 + 1] = f.y; v[j * 4 + 2] = f.z; v[j * 4 + 3] = f.w;
                }
            } else if (seg == 6) {
                float4 f = *reinterpret_cast<const float4*>(xr + 96);
                v[0] = f.x; v[1] = f.y; v[2] = f.z; v[3] = f.w;
            }
        }
        unsigned short o[16];
#pragma unroll
        for (int i = 0; i < 16; i++) o[i] = f2bf(v[i]);
#pragma unroll
        for (int half = 0; half < 2; half++) {
            int g = seg * 2 + half;
            unsigned byte = r * 256 + (((unsigned)g * 16) ^ (((unsigned)r & 7) << 4));
            *reinterpret_cast<short8_t*>(reinterpret_cast<char*>(sX) + byte) =
                *reinterpret_cast<const short8_t*>(&o[half * 8]);
        }
    }
    __syncthreads();

    f32x4 acc[2][2];
#pragma unroll
    for (int rt = 0; rt < 2; rt++)
#pragma unroll
        for (int ci = 0; ci < 2; ci++) acc[rt][ci] = (f32x4){0.f, 0.f, 0.f, 0.f};

#pragma unroll
    for (int ks = 0; ks < 4; ks++) {
        short8_t af[2];
#pragma unroll
        for (int rt = 0; rt < 2; rt++) {
            int r = rt * 16 + cc;
            unsigned byte = r * 256 + (((unsigned)(ks * 64 + kg * 16)) ^ (((unsigned)r & 7) << 4));
            af[rt] = *reinterpret_cast<const short8_t*>(reinterpret_cast<const char*>(sX) + byte);
        }
#pragma unroll
        for (int rt = 0; rt < 2; rt++)
#pragma unroll
            for (int ci = 0; ci < 2; ci++)
                acc[rt][ci] = __builtin_amdgcn_mfma_f32_16x16x32_bf16(af[rt], bfrag[ci][ks],
                                                                      acc[rt][ci], 0, 0, 0);
    }

#pragma unroll
    for (int rt = 0; rt < 2; rt++)
#pragma unroll
        for (int ci = 0; ci < 2; ci++) {
            int col = 32 * w + ci * 16 + cc;
            float bv = b[col];
#pragma unroll
            for (int reg = 0; reg < 4; reg++) {
                int row = row0 + rt * 16 + kg * 4 + reg;
                if (row < n) {
                    float v = acc[rt][ci][reg] + bv;
                    inp[(size_t)row * HIDC + col] = f2bf(v);
                    h[(size_t)row * HIDC + col] = f2bf(fmaxf(v, 0.f));
                }
            }
        }
}

// ---------------- Fused SAGE layer: gather(mean) -> LDS -> MFMA -> h_out ----------------
// Block = 32 nodes. Phase 1: wave w aggregates nodes [row0+8w, row0+8w+8) into swizzled LDS;
// h rows staged in parallel. Phase 2: MFMA (same verified fragment recipe).
// h double-buffered across layers (gather reads h_in while epilogue writes h_out).

__global__ __launch_bounds__(256) void k_sage_fused(const unsigned short* __restrict__ h_in,
                                                    unsigned short* __restrict__ h_out,
                                                    const unsigned short* __restrict__ inp,
                                                    const int* __restrict__ csr, const int* __restrict__ offs,
                                                    const float* __restrict__ invdeg,
                                                    const unsigned short* __restrict__ wt,  // [2][128][128]
                                                    const float* __restrict__ bl, int n) {
    __shared__ unsigned short sA[2][32 * 128];   // [0]=agg, [1]=h
    int t = threadIdx.x;
    int w = t >> 6, lane = t & 63;
    int cc = lane & 15, kg = lane >> 4;
    int row0 = blockIdx.x * 32;

    // B fragments
    short8_t bfrag[2][2][4];
#pragma unroll
    for (int s = 0; s < 2; s++)
#pragma unroll
        for (int ci = 0; ci < 2; ci++) {
            int ncol = 32 * w + ci * 16 + cc;
            const unsigned short* bp = wt + s * 16384 + ncol * 128 + kg * 8;
#pragma unroll
            for (int ks = 0; ks < 4; ks++)
                bfrag[s][ci][ks] = *reinterpret_cast<const short8_t*>(bp + ks * 32);
        }

    // stage h rows (self features) into sA[1]
    for (int c = t; c < 512; c += 256) {
        int r = c >> 4, g = c & 15;
        int row = row0 + r;
        unsigned byte = r * 256 + (((unsigned)g * 16) ^ (((unsigned)r & 7) << 4));
        short8_t vh = {0, 0, 0, 0, 0, 0, 0, 0};
        if (row < n) vh = *reinterpret_cast<const short8_t*>(h_in + (size_t)row * HIDC + g * 8);
        *reinterpret_cast<short8_t*>(reinterpret_cast<char*>(&sA[1][0]) + byte) = vh;
    }

    // gather phase: wave w handles 8 nodes; q = edge slot, c16 = chunk
    {
        int q = lane >> 4, c16 = lane & 15;
#pragma unroll
        for (int i = 0; i < 8; i++) {
            int v = row0 + w * 8 + i;
            float acc[8] = {0, 0, 0, 0, 0, 0, 0, 0};
            if (v < n) {
                int e0 = offs[v], e1 = offs[v + 1];
                for (int e = e0 + q; e < e1; e += 8) {
                    int s0 = csr[e];
                    bool has2 = (e + 4) < e1;
                    int s1 = has2 ? csr[e + 4] : s0;
                    short8_t t0 = *reinterpret_cast<const short8_t*>(h_in + (size_t)s0 * HIDC + c16 * 8);
                    short8_t t1 = *reinterpret_cast<const short8_t*>(h_in + (size_t)s1 * HIDC + c16 * 8);
#pragma unroll
                    for (int j = 0; j < 8; j++) {
                        acc[j] += bf2f((unsigned short)t0[j]);
                        if (has2) acc[j] += bf2f((unsigned short)t1[j]);
                    }
                }
            }
#pragma unroll
            for (int j = 0; j < 8; j++) {
                acc[j] += __shfl_xor(acc[j], 16);
                acc[j] += __shfl_xor(acc[j], 32);
            }
            if (q == 0) {
                float s = (v < n) ? invdeg[v] : 0.f;
                unsigned short o[8];
#pragma unroll
                for (int j = 0; j < 8; j++) o[j] = f2bf(acc[j] * s);
                int r = w * 8 + i;
                unsigned byte = r * 256 + (((unsigned)c16 * 16) ^ (((unsigned)r & 7) << 4));
                *reinterpret_cast<short8_t*>(reinterpret_cast<char*>(&sA[0][0]) + byte) =
                    *reinterpret_cast<const short8_t*>(o);
            }
        }
    }
    __syncthreads();

    f32x4 acc[2][2];
#pragma unroll
    for (int rt = 0; rt < 2; rt++)
#pragma unroll
        for (int ci = 0; ci < 2; ci++) acc[rt][ci] = (f32x4){0.f, 0.f, 0.f, 0.f};

#pragma unroll
    for (int ks = 0; ks < 4; ks++) {
        short8_t af[2][2];
#pragma unroll
        for (int s = 0; s < 2; s++)
#pragma unroll
            for (int rt = 0; rt < 2; rt++) {
                int r = rt * 16 + cc;
                unsigned byte = r * 256 + (((unsigned)(ks * 64 + kg * 16)) ^ (((unsigned)r & 7) << 4));
                af[s][rt] = *reinterpret_cast<const short8_t*>(reinterpret_cast<const char*>(&sA[s][0]) + byte);
            }
#pragma unroll
        for (int s = 0; s < 2; s++)
#pragma unroll
            for (int rt = 0; rt < 2; rt++)
#pragma unroll
                for (int ci = 0; ci < 2; ci++)
                    acc[rt][ci] = __builtin_amdgcn_mfma_f32_16x16x32_bf16(af[s][rt], bfrag[s][ci][ks],
                                                                          acc[rt][ci], 0, 0, 0);
    }

#pragma unroll
    for (int rt = 0; rt < 2; rt++)
#pragma unroll
        for (int ci = 0; ci < 2; ci++) {
            int col = 32 * w + ci * 16 + cc;
            float bv = bl[col];
#pragma unroll
            for (int reg = 0; reg < 4; reg++) {
                int row = row0 + rt * 16 + kg * 4 + reg;
                if (row < n) {
                    float v = acc[rt][ci][reg] + bv;
                    v = fmaxf(v, 0.f) + 0.2f * bf2f(inp[(size_t)row * HIDC + col]);
                    h_out[(size_t)row * HIDC + col] = f2bf(v);
                }
            }
        }
}

// ---------------- Fused output layer: gather -> LDS -> MFMA -> log_softmax ----------------
// Block = 64 nodes; wave w aggregates nodes [row0+16w, row0+16w+16) and computes rows [16w,16w+16).

__global__ __launch_bounds__(256) void k_out_fused(const unsigned short* __restrict__ h_in,
                                                   const int* __restrict__ csr, const int* __restrict__ offs,
                                                   const float* __restrict__ invdeg,
                                                   const unsigned short* __restrict__ wt2,  // [2][48][128]
                                                   const float* __restrict__ bl,
                                                   float* __restrict__ out, int n) {
    __shared__ unsigned short sA[2][64 * 128];
    int t = threadIdx.x;
    int w = t >> 6, lane = t & 63;
    int cc = lane & 15, kg = lane >> 4;
    int row0 = blockIdx.x * 64;

    short8_t bfrag[2][3][4];
#pragma unroll
    for (int s = 0; s < 2; s++)
#pragma unroll
        for (int ci = 0; ci < 3; ci++) {
            const unsigned short* bp = wt2 + s * (48 * 128) + (ci * 16 + cc) * 128 + kg * 8;
#pragma unroll
            for (int ks = 0; ks < 4; ks++)
                bfrag[s][ci][ks] = *reinterpret_cast<const short8_t*>(bp + ks * 32);
        }

    for (int c = t; c < 1024; c += 256) {
        int r = c >> 4, g = c & 15;
        int row = row0 + r;
        unsigned byte = r * 256 + (((unsigned)g * 16) ^ (((unsigned)r & 7) << 4));
        short8_t vh = {0, 0, 0, 0, 0, 0, 0, 0};
        if (row < n) vh = *reinterpret_cast<const short8_t*>(h_in + (size_t)row * HIDC + g * 8);
        *reinterpret_cast<short8_t*>(reinterpret_cast<char*>(&sA[1][0]) + byte) = vh;
    }

    {
        int q = lane >> 4, c16 = lane & 15;
#pragma unroll
        for (int i = 0; i < 16; i++) {
            int v = row0 + w * 16 + i;
            float acc[8] = {0, 0, 0, 0, 0, 0, 0, 0};
            if (v < n) {
                int e0 = offs[v], e1 = offs[v + 1];
                for (int e = e0 + q; e < e1; e += 8) {
                    int s0 = csr[e];
                    bool has2 = (e + 4) < e1;
                    int s1 = has2 ? csr[e + 4] : s0;
                    short8_t t0 = *reinterpret_cast<const short8_t*>(h_in + (size_t)s0 * HIDC + c16 * 8);
                    short8_t t1 = *reinterpret_cast<const short8_t*>(h_in + (size_t)s1 * HIDC + c16 * 8);
#pragma unroll
                    for (int j = 0; j < 8; j++) {
                        acc[j] += bf2f((unsigned short)t0[j]);
                        if (has2) acc[j] += bf2f((unsigned short)t1[j]);
                    }
                }
            }
#pragma unroll
            for (int j = 0; j < 8; j++) {
                acc[j] += __shfl_xor(acc[j], 16);
                acc[j] += __shfl_xor(acc[j], 32);
            }
            if (q == 0) {
                float s = (v < n) ? invdeg[v] : 0.f;
                unsigned short o[8];
#pragma unroll
                for (int j = 0; j < 8; j++) o[j] = f2bf(acc[j] * s);
                int r = w * 16 + i;
                unsigned byte = r * 256 + (((unsigned)c16 * 16) ^ (((unsigned)r & 7) << 4));
                *reinterpret_cast<short8_t*>(reinterpret_cast<char*>(&sA[0][0]) + byte) =
                    *reinterpret_cast<const short8_t*>(o);
            }
        }
    }
    __syncthreads();

    f32x4 acc[3];
#pragma unroll
    for (int ci = 0; ci < 3; ci++) acc[ci] = (f32x4){0.f, 0.f, 0.f, 0.f};

#pragma unroll
    for (int ks = 0; ks < 4; ks++) {
        short8_t af[2];
        int r = w * 16 + cc;
        unsigned byte = r * 256 + (((unsigned)(ks * 64 + kg * 16)) ^ (((unsigned)r & 7) << 4));
#pragma unroll
        for (int s = 0; s < 2; s++)
            af[s] = *reinterpret_cast<const short8_t*>(reinterpret_cast<const char*>(&sA[s][0]) + byte);
#pragma unroll
        for (int s = 0; s < 2; s++)
#pragma unroll
            for (int ci = 0; ci < 3; ci++)
                acc[ci] = __builtin_amdgcn_mfma_f32_16x16x32_bf16(af[s], bfrag[s][ci][ks], acc[ci], 0, 0, 0);
    }

#pragma unroll
    for (int reg = 0; reg < 4; reg++) {
        int row = row0 + w * 16 + kg * 4 + reg;
        float val[3];
        float m = -INFINITY;
#pragma unroll
        for (int ci = 0; ci < 3; ci++) {
            int col = ci * 16 + cc;
            val[ci] = (col < OUTC) ? (acc[ci][reg] + bl[col]) : -INFINITY;
            m = fmaxf(m, val[ci]);
        }
#pragma unroll
        for (int off = 1; off < 16; off <<= 1) m = fmaxf(m, __shfl_xor(m, off));
        float s = 0.f;
#pragma unroll
        for (int ci = 0; ci < 3; ci++) {
            int col = ci * 16 + cc;
            if (col < OUTC) s += __expf(val[ci] - m);
        }
#pragma unroll
        for (int off = 1; off < 16; off <<= 1) s += __shfl_xor(s, off);
        float lse = m + logf(s);
        if (row < n) {
#pragma unroll
            for (int ci = 0; ci < 3; ci++) {
                int col = ci * 16 + cc;
                if (col < OUTC) out[(size_t)row * OUTC + col] = val[ci] - lse;
            }
        }
    }
}

// ---------------- Launch ----------------

extern "C" void kernel_launch(void* const* d_in, const int* in_sizes, int n_in,
                              void* d_out, int out_size, void* d_ws, size_t ws_size,
                              hipStream_t stream) {
    const float* x        = (const float*)d_in[0];
    const int*   ei       = (const int*)d_in[1];
    const float* inproj_w = (const float*)d_in[2];
    const float* inproj_b = (const float*)d_in[3];
    const float* wl_h     = (const float*)d_in[4];
    const float* bl_h     = (const float*)d_in[5];
    const float* wr_h     = (const float*)d_in[6];
    const float* wl_out   = (const float*)d_in[7];
    const float* bl_out   = (const float*)d_in[8];
    const float* wr_out   = (const float*)d_in[9];
    float* out = (float*)d_out;

    int n  = in_sizes[0] / INC;   // 100000
    int ne = in_sizes[1] / 2;     // 1600000
    const int* src = ei;
    const int* dst = ei + ne;

    char* ws = (char*)d_ws;
    size_t off = 0;
    auto alloc = [&](size_t bytes) -> void* {
        void* p = ws + off;
        off = (off + bytes + 255) & ~(size_t)255;
        return p;
    };
    unsigned short* inp    = (unsigned short*)alloc((size_t)n * HIDC * 2);
    unsigned short* h_a    = (unsigned short*)alloc((size_t)n * HIDC * 2);
    unsigned short* h_b    = (unsigned short*)alloc((size_t)n * HIDC * 2);
    unsigned short* wt     = (unsigned short*)alloc((size_t)6 * 16384 * 2);
    unsigned short* wt2    = (unsigned short*)alloc((size_t)2 * 48 * 128 * 2);
    unsigned short* wtin   = (unsigned short*)alloc((size_t)128 * 128 * 2);
    int*   deg    = (int*)alloc((size_t)n * 4);
    float* invdeg = (float*)alloc((size_t)n * 4);
    int*   local_s= (int*)alloc((size_t)n * 4);
    int*   bsum   = (int*)alloc(512 * 4);
    int*   offs   = (int*)alloc((size_t)(n + 1) * 4);
    int*   curs   = (int*)alloc((size_t)n * 4);
    int*   csr    = (int*)alloc((size_t)ne * 4);

    hipMemsetAsync(deg, 0, (size_t)n * 4, stream);
    hipMemsetAsync(curs, 0, (size_t)n * 4, stream);

    int nbE = (ne + 255) / 256;
    int nbN = (n + 255) / 256;
    k_deg<<<nbE, 256, 0, stream>>>(dst, deg, ne);
    k_scan1<<<nbN, 256, 0, stream>>>(deg, local_s, bsum, n);
    k_scan2<<<1, 512, 0, stream>>>(bsum, nbN);
    k_scan3<<<nbN, 256, 0, stream>>>(local_s, bsum, offs, n, ne);
    k_invdeg<<<nbN, 256, 0, stream>>>(deg, invdeg, n);

    int psize = (n + 7) / 8;
    int nchunk = 256;
    int ch = (ne + nchunk - 1) / nchunk;
    k_fill<<<nchunk * 8, 256, 0, stream>>>(src, dst, offs, curs, csr, ne, psize, ch);

    k_prepw<<<(6 * 16384 + 255) / 256, 256, 0, stream>>>(wl_h, wr_h, wt);
    k_prepw_out<<<(2 * 48 * 128 + 255) / 256, 256, 0, stream>>>(wl_out, wr_out, wt2);
    k_prepw_in<<<(128 * 128 + 255) / 256, 256, 0, stream>>>(inproj_w, wtin);

    int nbT = (n + 31) / 32;
    int nbO = (n + 63) / 64;
    k_inproj_mfma<<<nbT, 256, 0, stream>>>(x, wtin, inproj_b, inp, h_a, n);

    unsigned short* h_cur = h_a;
    unsigned short* h_nxt = h_b;
    for (int l = 0; l < 3; ++l) {
        k_sage_fused<<<nbT, 256, 0, stream>>>(h_cur, h_nxt, inp, csr, offs, invdeg,
                                              wt + (size_t)l * 2 * 16384,
                                              bl_h + (size_t)l * HIDC, n);
        unsigned short* tmp = h_cur; h_cur = h_nxt; h_nxt = tmp;
    }
    k_out_fused<<<nbO, 256, 0, stream>>>(h_cur, csr, offs, invdeg, wt2, bl_out, out, n);
}

// Round 9
// 595.115 us; speedup vs baseline: 1.2956x; 1.2956x over previous
//
#include <hip/hip_runtime.h>
#include <math.h>

#define HIDC 128
#define INC 100
#define OUTC 47

typedef __attribute__((ext_vector_type(8))) short short8_t;   // 8 bf16 (4 VGPRs)
typedef __attribute__((ext_vector_type(4))) float f32x4;      // MFMA accumulator

__device__ inline unsigned short f2bf(float f) {
    unsigned u = __builtin_bit_cast(unsigned, f);
    unsigned r = (u + 0x7FFFu + ((u >> 16) & 1u)) >> 16;      // RNE
    return (unsigned short)r;
}
__device__ inline float bf2f(unsigned short s) {
    unsigned u = ((unsigned)s) << 16;
    return __builtin_bit_cast(float, u);
}

// ---------------- CSR build ----------------

__global__ __launch_bounds__(256) void k_deg(const int* __restrict__ dst, int* __restrict__ deg, int ne) {
    int e = blockIdx.x * 256 + threadIdx.x;
    if (e < ne) atomicAdd(&deg[dst[e]], 1);
}

__global__ __launch_bounds__(256) void k_scan1(const int* __restrict__ deg, int* __restrict__ local_s,
                                               int* __restrict__ bsum, int n) {
    __shared__ int s[256];
    int t = threadIdx.x;
    int i = blockIdx.x * 256 + t;
    int v = (i < n) ? deg[i] : 0;
    s[t] = v;
    __syncthreads();
    for (int off = 1; off < 256; off <<= 1) {
        int add = (t >= off) ? s[t - off] : 0;
        __syncthreads();
        s[t] += add;
        __syncthreads();
    }
    if (i < n) local_s[i] = s[t] - v;
    if (t == 255) bsum[blockIdx.x] = s[255];
}

__global__ __launch_bounds__(512) void k_scan2(int* __restrict__ bsum, int nb) {
    __shared__ int s[512];
    int t = threadIdx.x;
    int v = (t < nb) ? bsum[t] : 0;
    s[t] = v;
    __syncthreads();
    for (int off = 1; off < 512; off <<= 1) {
        int add = (t >= off) ? s[t - off] : 0;
        __syncthreads();
        s[t] += add;
        __syncthreads();
    }
    if (t < nb) bsum[t] = s[t] - v;
}

__global__ __launch_bounds__(256) void k_scan3(const int* __restrict__ local_s, const int* __restrict__ bsum,
                                               int* __restrict__ offs, int n, int ne) {
    int i = blockIdx.x * 256 + threadIdx.x;
    if (i < n) offs[i] = local_s[i] + bsum[blockIdx.x];
    if (i == 0) offs[n] = ne;
}

__global__ __launch_bounds__(256) void k_invdeg(const int* __restrict__ deg, float* __restrict__ invdeg, int n) {
    int i = blockIdx.x * 256 + threadIdx.x;
    if (i < n) invdeg[i] = 1.0f / (float)max(deg[i], 1);
}

// Partitioned fill, CHUNKED mapping test: partition p = blockIdx>>8 (256 consecutive
// blocks per partition). If dispatch assigns consecutive blocks to the same XCD
// (chunked hypothesis), all writers of a csr slice share one L2 -> write combining.

__global__ __launch_bounds__(256) void k_fill(const int* __restrict__ src, const int* __restrict__ dst,
                                              const int* __restrict__ offs, int* __restrict__ curs,
                                              int* __restrict__ csr, int ne, int psize, int ch) {
    int p = blockIdx.x >> 8;       // 8 partitions, chunked
    int chunk = blockIdx.x & 255;  // 256 chunks each
    int lo = p * psize;
    int e0 = chunk * ch;
    int e1 = min(ne, e0 + ch);
    for (int e = e0 + threadIdx.x; e < e1; e += 256) {
        int d = dst[e];
        if ((unsigned)(d - lo) < (unsigned)psize) {
            int pos = atomicAdd(&curs[d], 1);
            csr[offs[d] + pos] = src[e];
        }
    }
}

// ---------------- Weight prep ----------------

__global__ __launch_bounds__(256) void k_prepw(const float* __restrict__ wl_h, const float* __restrict__ wr_h,
                                               unsigned short* __restrict__ wt) {
    int idx = blockIdx.x * 256 + threadIdx.x;
    if (idx >= 6 * 16384) return;
    int m = idx >> 14, rem = idx & 16383;
    int l = m >> 1, s = m & 1;
    const float* srcm = (s == 0 ? wl_h : wr_h) + (size_t)l * 16384;
    wt[idx] = f2bf(srcm[(rem & 127) * 128 + (rem >> 7)]);
}

__global__ __launch_bounds__(256) void k_prepw_out(const float* __restrict__ wl_out,
                                                   const float* __restrict__ wr_out,
                                                   unsigned short* __restrict__ wt2) {
    int idx = blockIdx.x * 256 + threadIdx.x;
    if (idx >= 2 * 48 * 128) return;
    int s = idx / (48 * 128), rem = idx % (48 * 128);
    int nc = rem >> 7, k = rem & 127;
    const float* srcm = (s == 0) ? wl_out : wr_out;
    wt2[idx] = (nc < OUTC) ? f2bf(srcm[k * OUTC + nc]) : 0;
}

__global__ __launch_bounds__(256) void k_prepw_in(const float* __restrict__ w,
                                                  unsigned short* __restrict__ wtin) {
    int idx = blockIdx.x * 256 + threadIdx.x;
    if (idx >= 128 * 128) return;
    int nc = idx >> 7, k = idx & 127;
    wtin[idx] = (k < INC) ? f2bf(w[k * HIDC + nc]) : 0;
}

// ---------------- Aggregation (pull, mean): wave per node, bf16 rows, 8 edges/iter ----------------

__global__ __launch_bounds__(256) void k_agg(const unsigned short* __restrict__ h, const int* __restrict__ csr,
                                             const int* __restrict__ offs, const float* __restrict__ invdeg,
                                             unsigned short* __restrict__ agg, int n) {
    int wv = threadIdx.x >> 6, lane = threadIdx.x & 63;
    int v = blockIdx.x * 4 + wv;
    if (v >= n) return;
    int q = lane >> 4, c = lane & 15;   // q: edge slot, c: 16B chunk (8 bf16)
    int e0 = offs[v], e1 = offs[v + 1];
    float acc[8] = {0, 0, 0, 0, 0, 0, 0, 0};
    for (int e = e0 + q; e < e1; e += 8) {
        int s0 = csr[e];
        bool has2 = (e + 4) < e1;
        int s1 = has2 ? csr[e + 4] : s0;
        short8_t t0 = *reinterpret_cast<const short8_t*>(h + (size_t)s0 * HIDC + c * 8);
        short8_t t1 = *reinterpret_cast<const short8_t*>(h + (size_t)s1 * HIDC + c * 8);
#pragma unroll
        for (int i = 0; i < 8; i++) {
            acc[i] += bf2f((unsigned short)t0[i]);
            if (has2) acc[i] += bf2f((unsigned short)t1[i]);
        }
    }
#pragma unroll
    for (int i = 0; i < 8; i++) {
        acc[i] += __shfl_xor(acc[i], 16);
        acc[i] += __shfl_xor(acc[i], 32);
    }
    if (q == 0) {
        float s = invdeg[v];
        unsigned short o[8];
#pragma unroll
        for (int i = 0; i < 8; i++) o[i] = f2bf(acc[i] * s);
        *reinterpret_cast<short8_t*>(agg + (size_t)v * HIDC + c * 8) = *reinterpret_cast<const short8_t*>(o);
    }
}

// ---------------- Input projection via MFMA ----------------

__global__ __launch_bounds__(256) void k_inproj_mfma(const float* __restrict__ x,
                                                     const unsigned short* __restrict__ wtin, // [128][128]
                                                     const float* __restrict__ b,
                                                     unsigned short* __restrict__ inp,
                                                     unsigned short* __restrict__ h, int n) {
    __shared__ unsigned short sX[32 * 128];
    int t = threadIdx.x;
    int w = t >> 6, lane = t & 63;
    int cc = lane & 15, kg = lane >> 4;
    int row0 = blockIdx.x * 32;

    short8_t bfrag[2][4];
#pragma unroll
    for (int ci = 0; ci < 2; ci++) {
        int ncol = 32 * w + ci * 16 + cc;
        const unsigned short* bp = wtin + ncol * 128 + kg * 8;
#pragma unroll
        for (int ks = 0; ks < 4; ks++)
            bfrag[ci][ks] = *reinterpret_cast<const short8_t*>(bp + ks * 32);
    }

    {
        int r = t >> 3, seg = t & 7;
        int row = row0 + r;
        float v[16];
#pragma unroll
        for (int i = 0; i < 16; i++) v[i] = 0.f;
        if (row < n) {
            const float* xr = x + (size_t)row * INC;
            if (seg < 6) {
#pragma unroll
                for (int j = 0; j < 4; j++) {
                    float4 f = *reinterpret_cast<const float4*>(xr + seg * 16 + j * 4);
                    v[j * 4 + 0] = f.x; v[j * 4 + 1] = f.y; v[j * 4 + 2] = f.z; v[j * 4 + 3] = f.w;
                }
            } else if (seg == 6) {
                float4 f = *reinterpret_cast<const float4*>(xr + 96);
                v[0] = f.x; v[1] = f.y; v[2] = f.z; v[3] = f.w;
            }
        }
        unsigned short o[16];
#pragma unroll
        for (int i = 0; i < 16; i++) o[i] = f2bf(v[i]);
#pragma unroll
        for (int half = 0; half < 2; half++) {
            int g = seg * 2 + half;
            unsigned byte = r * 256 + (((unsigned)g * 16) ^ (((unsigned)r & 7) << 4));
            *reinterpret_cast<short8_t*>(reinterpret_cast<char*>(sX) + byte) =
                *reinterpret_cast<const short8_t*>(&o[half * 8]);
        }
    }
    __syncthreads();

    f32x4 acc[2][2];
#pragma unroll
    for (int rt = 0; rt < 2; rt++)
#pragma unroll
        for (int ci = 0; ci < 2; ci++) acc[rt][ci] = (f32x4){0.f, 0.f, 0.f, 0.f};

#pragma unroll
    for (int ks = 0; ks < 4; ks++) {
        short8_t af[2];
#pragma unroll
        for (int rt = 0; rt < 2; rt++) {
            int r = rt * 16 + cc;
            unsigned byte = r * 256 + (((unsigned)(ks * 64 + kg * 16)) ^ (((unsigned)r & 7) << 4));
            af[rt] = *reinterpret_cast<const short8_t*>(reinterpret_cast<const char*>(sX) + byte);
        }
#pragma unroll
        for (int rt = 0; rt < 2; rt++)
#pragma unroll
            for (int ci = 0; ci < 2; ci++)
                acc[rt][ci] = __builtin_amdgcn_mfma_f32_16x16x32_bf16(af[rt], bfrag[ci][ks],
                                                                      acc[rt][ci], 0, 0, 0);
    }

#pragma unroll
    for (int rt = 0; rt < 2; rt++)
#pragma unroll
        for (int ci = 0; ci < 2; ci++) {
            int col = 32 * w + ci * 16 + cc;
            float bv = b[col];
#pragma unroll
            for (int reg = 0; reg < 4; reg++) {
                int row = row0 + rt * 16 + kg * 4 + reg;
                if (row < n) {
                    float v = acc[rt][ci][reg] + bv;
                    inp[(size_t)row * HIDC + col] = f2bf(v);
                    h[(size_t)row * HIDC + col] = f2bf(fmaxf(v, 0.f));
                }
            }
        }
}

// ---------------- Hidden SAGE layer via MFMA (inp bf16) ----------------

__global__ __launch_bounds__(256) void k_sage_mfma(const unsigned short* __restrict__ agg,
                                                   unsigned short* __restrict__ h,
                                                   const unsigned short* __restrict__ inp,
                                                   const unsigned short* __restrict__ wt,  // [2][128][128]
                                                   const float* __restrict__ bl, int n) {
    __shared__ unsigned short sA[2][32 * 128];
    int t = threadIdx.x;
    int w = t >> 6, lane = t & 63;
    int cc = lane & 15, kg = lane >> 4;
    int row0 = blockIdx.x * 32;

    short8_t bfrag[2][2][4];
#pragma unroll
    for (int s = 0; s < 2; s++)
#pragma unroll
        for (int ci = 0; ci < 2; ci++) {
            int ncol = 32 * w + ci * 16 + cc;
            const unsigned short* bp = wt + s * 16384 + ncol * 128 + kg * 8;
#pragma unroll
            for (int ks = 0; ks < 4; ks++)
                bfrag[s][ci][ks] = *reinterpret_cast<const short8_t*>(bp + ks * 32);
        }

    for (int c = t; c < 512; c += 256) {
        int r = c >> 4, g = c & 15;
        int row = row0 + r;
        unsigned byte = r * 256 + (((unsigned)g * 16) ^ (((unsigned)r & 7) << 4));
        short8_t va = {0, 0, 0, 0, 0, 0, 0, 0}, vh = va;
        if (row < n) {
            va = *reinterpret_cast<const short8_t*>(agg + (size_t)row * HIDC + g * 8);
            vh = *reinterpret_cast<const short8_t*>(h + (size_t)row * HIDC + g * 8);
        }
        *reinterpret_cast<short8_t*>(reinterpret_cast<char*>(&sA[0][0]) + byte) = va;
        *reinterpret_cast<short8_t*>(reinterpret_cast<char*>(&sA[1][0]) + byte) = vh;
    }
    __syncthreads();

    f32x4 acc[2][2];
#pragma unroll
    for (int rt = 0; rt < 2; rt++)
#pragma unroll
        for (int ci = 0; ci < 2; ci++) acc[rt][ci] = (f32x4){0.f, 0.f, 0.f, 0.f};

#pragma unroll
    for (int ks = 0; ks < 4; ks++) {
        short8_t af[2][2];
#pragma unroll
        for (int s = 0; s < 2; s++)
#pragma unroll
            for (int rt = 0; rt < 2; rt++) {
                int r = rt * 16 + cc;
                unsigned byte = r * 256 + (((unsigned)(ks * 64 + kg * 16)) ^ (((unsigned)r & 7) << 4));
                af[s][rt] = *reinterpret_cast<const short8_t*>(reinterpret_cast<const char*>(&sA[s][0]) + byte);
            }
#pragma unroll
        for (int s = 0; s < 2; s++)
#pragma unroll
            for (int rt = 0; rt < 2; rt++)
#pragma unroll
                for (int ci = 0; ci < 2; ci++)
                    acc[rt][ci] = __builtin_amdgcn_mfma_f32_16x16x32_bf16(af[s][rt], bfrag[s][ci][ks],
                                                                          acc[rt][ci], 0, 0, 0);
    }

#pragma unroll
    for (int rt = 0; rt < 2; rt++)
#pragma unroll
        for (int ci = 0; ci < 2; ci++) {
            int col = 32 * w + ci * 16 + cc;
            float bv = bl[col];
#pragma unroll
            for (int reg = 0; reg < 4; reg++) {
                int row = row0 + rt * 16 + kg * 4 + reg;
                if (row < n) {
                    float v = acc[rt][ci][reg] + bv;
                    v = fmaxf(v, 0.f) + 0.2f * bf2f(inp[(size_t)row * HIDC + col]);
                    h[(size_t)row * HIDC + col] = f2bf(v);
                }
            }
        }
}

// ---------------- Output layer via MFMA + in-register log_softmax ----------------

__global__ __launch_bounds__(256) void k_out_mfma(const unsigned short* __restrict__ agg,
                                                  const unsigned short* __restrict__ h,
                                                  const unsigned short* __restrict__ wt2,  // [2][48][128]
                                                  const float* __restrict__ bl,
                                                  float* __restrict__ out, int n) {
    __shared__ unsigned short sA[2][64 * 128];
    int t = threadIdx.x;
    int w = t >> 6, lane = t & 63;
    int cc = lane & 15, kg = lane >> 4;
    int row0 = blockIdx.x * 64;

    short8_t bfrag[2][3][4];
#pragma unroll
    for (int s = 0; s < 2; s++)
#pragma unroll
        for (int ci = 0; ci < 3; ci++) {
            const unsigned short* bp = wt2 + s * (48 * 128) + (ci * 16 + cc) * 128 + kg * 8;
#pragma unroll
            for (int ks = 0; ks < 4; ks++)
                bfrag[s][ci][ks] = *reinterpret_cast<const short8_t*>(bp + ks * 32);
        }

    for (int c = t; c < 1024; c += 256) {
        int r = c >> 4, g = c & 15;
        int row = row0 + r;
        unsigned byte = r * 256 + (((unsigned)g * 16) ^ (((unsigned)r & 7) << 4));
        short8_t va = {0, 0, 0, 0, 0, 0, 0, 0}, vh = va;
        if (row < n) {
            va = *reinterpret_cast<const short8_t*>(agg + (size_t)row * HIDC + g * 8);
            vh = *reinterpret_cast<const short8_t*>(h + (size_t)row * HIDC + g * 8);
        }
        *reinterpret_cast<short8_t*>(reinterpret_cast<char*>(&sA[0][0]) + byte) = va;
        *reinterpret_cast<short8_t*>(reinterpret_cast<char*>(&sA[1][0]) + byte) = vh;
    }
    __syncthreads();

    f32x4 acc[3];
#pragma unroll
    for (int ci = 0; ci < 3; ci++) acc[ci] = (f32x4){0.f, 0.f, 0.f, 0.f};

#pragma unroll
    for (int ks = 0; ks < 4; ks++) {
        short8_t af[2];
        int r = w * 16 + cc;
        unsigned byte = r * 256 + (((unsigned)(ks * 64 + kg * 16)) ^ (((unsigned)r & 7) << 4));
#pragma unroll
        for (int s = 0; s < 2; s++)
            af[s] = *reinterpret_cast<const short8_t*>(reinterpret_cast<const char*>(&sA[s][0]) + byte);
#pragma unroll
        for (int s = 0; s < 2; s++)
#pragma unroll
            for (int ci = 0; ci < 3; ci++)
                acc[ci] = __builtin_amdgcn_mfma_f32_16x16x32_bf16(af[s], bfrag[s][ci][ks], acc[ci], 0, 0, 0);
    }

#pragma unroll
    for (int reg = 0; reg < 4; reg++) {
        int row = row0 + w * 16 + kg * 4 + reg;
        float val[3];
        float m = -INFINITY;
#pragma unroll
        for (int ci = 0; ci < 3; ci++) {
            int col = ci * 16 + cc;
            val[ci] = (col < OUTC) ? (acc[ci][reg] + bl[col]) : -INFINITY;
            m = fmaxf(m, val[ci]);
        }
#pragma unroll
        for (int off = 1; off < 16; off <<= 1) m = fmaxf(m, __shfl_xor(m, off));
        float s = 0.f;
#pragma unroll
        for (int ci = 0; ci < 3; ci++) {
            int col = ci * 16 + cc;
            if (col < OUTC) s += __expf(val[ci] - m);
        }
#pragma unroll
        for (int off = 1; off < 16; off <<= 1) s += __shfl_xor(s, off);
        float lse = m + logf(s);
        if (row < n) {
#pragma unroll
            for (int ci = 0; ci < 3; ci++) {
                int col = ci * 16 + cc;
                if (col < OUTC) out[(size_t)row * OUTC + col] = val[ci] - lse;
            }
        }
    }
}

// ---------------- Launch ----------------

extern "C" void kernel_launch(void* const* d_in, const int* in_sizes, int n_in,
                              void* d_out, int out_size, void* d_ws, size_t ws_size,
                              hipStream_t stream) {
    const float* x        = (const float*)d_in[0];
    const int*   ei       = (const int*)d_in[1];
    const float* inproj_w = (const float*)d_in[2];
    const float* inproj_b = (const float*)d_in[3];
    const float* wl_h     = (const float*)d_in[4];
    const float* bl_h     = (const float*)d_in[5];
    const float* wr_h     = (const float*)d_in[6];
    const float* wl_out   = (const float*)d_in[7];
    const float* bl_out   = (const float*)d_in[8];
    const float* wr_out   = (const float*)d_in[9];
    float* out = (float*)d_out;

    int n  = in_sizes[0] / INC;   // 100000
    int ne = in_sizes[1] / 2;     // 1600000
    const int* src = ei;
    const int* dst = ei + ne;

    char* ws = (char*)d_ws;
    size_t off = 0;
    auto alloc = [&](size_t bytes) -> void* {
        void* p = ws + off;
        off = (off + bytes + 255) & ~(size_t)255;
        return p;
    };
    unsigned short* inp    = (unsigned short*)alloc((size_t)n * HIDC * 2);
    unsigned short* h      = (unsigned short*)alloc((size_t)n * HIDC * 2);
    unsigned short* agg    = (unsigned short*)alloc((size_t)n * HIDC * 2);
    unsigned short* wt     = (unsigned short*)alloc((size_t)6 * 16384 * 2);
    unsigned short* wt2    = (unsigned short*)alloc((size_t)2 * 48 * 128 * 2);
    unsigned short* wtin   = (unsigned short*)alloc((size_t)128 * 128 * 2);
    int*   deg    = (int*)alloc((size_t)n * 4);
    float* invdeg = (float*)alloc((size_t)n * 4);
    int*   local_s= (int*)alloc((size_t)n * 4);
    int*   bsum   = (int*)alloc(512 * 4);
    int*   offs   = (int*)alloc((size_t)(n + 1) * 4);
    int*   curs   = (int*)alloc((size_t)n * 4);
    int*   csr    = (int*)alloc((size_t)ne * 4);

    hipMemsetAsync(deg, 0, (size_t)n * 4, stream);
    hipMemsetAsync(curs, 0, (size_t)n * 4, stream);

    int nbE = (ne + 255) / 256;
    int nbN = (n + 255) / 256;
    k_deg<<<nbE, 256, 0, stream>>>(dst, deg, ne);
    k_scan1<<<nbN, 256, 0, stream>>>(deg, local_s, bsum, n);
    k_scan2<<<1, 512, 0, stream>>>(bsum, nbN);
    k_scan3<<<nbN, 256, 0, stream>>>(local_s, bsum, offs, n, ne);
    k_invdeg<<<nbN, 256, 0, stream>>>(deg, invdeg, n);

    // chunked-partition fill: blocks [256p, 256p+256) all handle dst partition p
    int psize = (n + 7) / 8;
    int nchunk = 256;
    int ch = (ne + nchunk - 1) / nchunk;
    k_fill<<<nchunk * 8, 256, 0, stream>>>(src, dst, offs, curs, csr, ne, psize, ch);

    k_prepw<<<(6 * 16384 + 255) / 256, 256, 0, stream>>>(wl_h, wr_h, wt);
    k_prepw_out<<<(2 * 48 * 128 + 255) / 256, 256, 0, stream>>>(wl_out, wr_out, wt2);
    k_prepw_in<<<(128 * 128 + 255) / 256, 256, 0, stream>>>(inproj_w, wtin);

    int nbA = (n + 3) / 4;
    int nbT = (n + 31) / 32;
    int nbO = (n + 63) / 64;
    k_inproj_mfma<<<nbT, 256, 0, stream>>>(x, wtin, inproj_b, inp, h, n);
    for (int l = 0; l < 3; ++l) {
        k_agg<<<nbA, 256, 0, stream>>>(h, csr, offs, invdeg, agg, n);
        k_sage_mfma<<<nbT, 256, 0, stream>>>(agg, h, inp, wt + (size_t)l * 2 * 16384,
                                             bl_h + (size_t)l * HIDC, n);
    }
    k_agg<<<nbA, 256, 0, stream>>>(h, csr, offs, invdeg, agg, n);
    k_out_mfma<<<nbO, 256, 0, stream>>>(agg, h, wt2, bl_out, out, n);
}